// Round 1
// baseline (4931.357 us; speedup 1.0000x reference)
//
#include <hip/hip_runtime.h>
#include <math.h>

#define HID 128

__device__ __forceinline__ float bf2f(unsigned int u16) {
  union { unsigned int i; float f; } x; x.i = u16 << 16; return x.f;
}
__device__ __forceinline__ unsigned short f2bf(float f) {
  union { float f; unsigned int i; } x; x.f = f;
  unsigned int i = x.i;
  unsigned int r = i + 0x7FFFu + ((i >> 16) & 1u);
  return (unsigned short)(r >> 16);
}

// ---------------- lin0: h = x @ W(70x128) + b ----------------
__global__ __launch_bounds__(128) void lin0_kernel(
    const float* __restrict__ x, const float* __restrict__ W,
    const float* __restrict__ b, float* __restrict__ h, int N, int inF)
{
  __shared__ float xs[128];
  int n = blockIdx.x;
  int t = threadIdx.x;
  if (t < inF) xs[t] = x[(size_t)n * inF + t];
  __syncthreads();
  float acc = b[t];
  for (int k = 0; k < inF; k++) acc += xs[k] * W[(size_t)k * 128 + t];
  h[(size_t)n * 128 + t] = acc;
}

// ---------------- fused projection GEMM ----------------
// A[M,128] fp32.  Output cols: [0,512)=q, [512,1024)=k, [1024,1536)=v (bf16),
// [1536,1664)=skip -> hnext (fp32).  BM=64, BN=64, BK=16, 256 threads.
__global__ __launch_bounds__(256) void proj_kernel(
    const float* __restrict__ A, int M,
    const float* __restrict__ Wq, const float* __restrict__ bq,
    const float* __restrict__ Wk, const float* __restrict__ bk,
    const float* __restrict__ Wv, const float* __restrict__ bv,
    const float* __restrict__ Ws, const float* __restrict__ bs,
    unsigned short* __restrict__ qo, unsigned short* __restrict__ ko,
    unsigned short* __restrict__ vo, float* __restrict__ hn)
{
  __shared__ float As[16][64];
  __shared__ float Bs[16][64];
  const int t = threadIdx.x;
  const int m0 = blockIdx.x * 64;
  const int n0 = blockIdx.y * 64;
  const int region = n0 >> 9;                 // 0=q 1=k 2=v 3=skip
  const float* B; const float* bias; int ldb;
  if (region == 0)      { B = Wq; bias = bq; ldb = 512; }
  else if (region == 1) { B = Wk; bias = bk; ldb = 512; }
  else if (region == 2) { B = Wv; bias = bv; ldb = 512; }
  else                  { B = Ws; bias = bs; ldb = 128; }
  const int cl = n0 - region * 512;           // local col base within matrix

  const int am = t >> 2;                      // 0..63
  const int ak = (t & 3) * 4;                 // 0,4,8,12
  const int bkr = t >> 4;                     // 0..15
  const int bn  = (t & 15) * 4;               // 0..60
  const int tx = t & 15, ty = t >> 4;

  const int arow = m0 + am;
  const bool avalid = arow < M;
  const float* Aptr = A + (size_t)arow * 128;

  float acc[4][4];
#pragma unroll
  for (int i = 0; i < 4; i++)
#pragma unroll
    for (int j = 0; j < 4; j++) acc[i][j] = 0.f;

  for (int k0 = 0; k0 < 128; k0 += 16) {
    float4 av = avalid ? *(const float4*)(Aptr + k0 + ak) : make_float4(0.f,0.f,0.f,0.f);
    float4 bv4 = *(const float4*)(B + (size_t)(k0 + bkr) * ldb + cl + bn);
    __syncthreads();   // protect LDS from previous iteration's readers
    As[ak+0][am] = av.x; As[ak+1][am] = av.y; As[ak+2][am] = av.z; As[ak+3][am] = av.w;
    *(float4*)(&Bs[bkr][bn]) = bv4;
    __syncthreads();
#pragma unroll
    for (int kk = 0; kk < 16; kk++) {
      const float4 a  = *(const float4*)(&As[kk][ty*4]);
      const float4 bb = *(const float4*)(&Bs[kk][tx*4]);
      acc[0][0] += a.x*bb.x; acc[0][1] += a.x*bb.y; acc[0][2] += a.x*bb.z; acc[0][3] += a.x*bb.w;
      acc[1][0] += a.y*bb.x; acc[1][1] += a.y*bb.y; acc[1][2] += a.y*bb.z; acc[1][3] += a.y*bb.w;
      acc[2][0] += a.z*bb.x; acc[2][1] += a.z*bb.y; acc[2][2] += a.z*bb.z; acc[2][3] += a.z*bb.w;
      acc[3][0] += a.w*bb.x; acc[3][1] += a.w*bb.y; acc[3][2] += a.w*bb.z; acc[3][3] += a.w*bb.w;
    }
  }

#pragma unroll
  for (int ii = 0; ii < 4; ii++) {
    int row = m0 + ty*4 + ii;
    if (row >= M) continue;
#pragma unroll
    for (int jj = 0; jj < 4; jj++) {
      int col = cl + tx*4 + jj;
      float val = acc[ii][jj] + bias[col];
      if (region == 0)      qo[(size_t)row*512 + col] = f2bf(val);
      else if (region == 1) ko[(size_t)row*512 + col] = f2bf(val);
      else if (region == 2) vo[(size_t)row*512 + col] = f2bf(val);
      else                  hn[(size_t)row*128 + col] = val;
    }
  }
}

// ---------------- edge alpha + exp + denom ----------------
// one wave per edge; lane covers 8 contiguous bf16 of q[dst]/k[src]
__global__ __launch_bounds__(256) void edge_alpha_kernel(
    const unsigned short* __restrict__ q, const unsigned short* __restrict__ k,
    const int* __restrict__ src, const int* __restrict__ dst,
    float* __restrict__ ebuf, float* __restrict__ den, int E)
{
  int e = (blockIdx.x * 256 + threadIdx.x) >> 6;
  int lane = threadIdx.x & 63;
  if (e >= E) return;
  int s = src[e], d = dst[e];
  const uint4 qv = *(const uint4*)(q + (size_t)d * 512 + lane * 8);
  const uint4 kv = *(const uint4*)(k + (size_t)s * 512 + lane * 8);
  float p = 0.f;
  p += bf2f(qv.x & 0xFFFFu) * bf2f(kv.x & 0xFFFFu);
  p += bf2f(qv.x >> 16)     * bf2f(kv.x >> 16);
  p += bf2f(qv.y & 0xFFFFu) * bf2f(kv.y & 0xFFFFu);
  p += bf2f(qv.y >> 16)     * bf2f(kv.y >> 16);
  p += bf2f(qv.z & 0xFFFFu) * bf2f(kv.z & 0xFFFFu);
  p += bf2f(qv.z >> 16)     * bf2f(kv.z >> 16);
  p += bf2f(qv.w & 0xFFFFu) * bf2f(kv.w & 0xFFFFu);
  p += bf2f(qv.w >> 16)     * bf2f(kv.w >> 16);
  p += __shfl_xor(p, 1);
  p += __shfl_xor(p, 2);
  p += __shfl_xor(p, 4);
  p += __shfl_xor(p, 8);
  if ((lane & 15) == 0) {
    int h = lane >> 4;
    float ev = expf(p * 0.08838834764831845f);  // 1/sqrt(128)
    ebuf[(size_t)e * 4 + h] = ev;
    atomicAdd(&den[(size_t)d * 4 + h], ev);
  }
}

// ---------------- edge aggregation: hnext[dst] += sum_h (a_h/4) * v[src,h,:] ----
__global__ __launch_bounds__(256) void edge_aggr_kernel(
    const unsigned short* __restrict__ v, const float* __restrict__ ebuf,
    const float* __restrict__ den, const int* __restrict__ src,
    const int* __restrict__ dst, float* __restrict__ hn, int E)
{
  int e = (blockIdx.x * 256 + threadIdx.x) >> 6;
  int lane = threadIdx.x & 63;
  if (e >= E) return;
  int s = src[e], d = dst[e];
  float4 ev = *(const float4*)(ebuf + (size_t)e * 4);
  float4 dn = *(const float4*)(den + (size_t)d * 4);
  float a0 = 0.25f * ev.x / dn.x;
  float a1 = 0.25f * ev.y / dn.y;
  float a2 = 0.25f * ev.z / dn.z;
  float a3 = 0.25f * ev.w / dn.w;
  const unsigned short* vp = v + (size_t)s * 512 + lane * 2;
  float c0 = 0.f, c1 = 0.f;
  unsigned int w;
  w = *(const unsigned int*)(vp + 0);   c0 += a0 * bf2f(w & 0xFFFFu); c1 += a0 * bf2f(w >> 16);
  w = *(const unsigned int*)(vp + 128); c0 += a1 * bf2f(w & 0xFFFFu); c1 += a1 * bf2f(w >> 16);
  w = *(const unsigned int*)(vp + 256); c0 += a2 * bf2f(w & 0xFFFFu); c1 += a2 * bf2f(w >> 16);
  w = *(const unsigned int*)(vp + 384); c0 += a3 * bf2f(w & 0xFFFFu); c1 += a3 * bf2f(w >> 16);
  float* hp = hn + (size_t)d * 128 + lane * 2;
  atomicAdd(hp, c0);
  atomicAdd(hp + 1, c1);
}

// ---------------- relu ----------------
__global__ __launch_bounds__(256) void relu_kernel(float* __restrict__ h, int n)
{
  int i = blockIdx.x * 256 + threadIdx.x;
  if (i < n) h[i] = fmaxf(h[i], 0.f);
}

// ---------------- pooling: emb[batch[n]] += h[n] (batch sorted) ----------------
__global__ __launch_bounds__(128) void pool_kernel(
    const float* __restrict__ h, const int* __restrict__ batch,
    float* __restrict__ emb, int N)
{
  int d = threadIdx.x;
  int n0 = blockIdx.x * 128;
  int n1 = min(n0 + 128, N);
  float acc = 0.f; int cur = -1;
  for (int n = n0; n < n1; n++) {
    int g = batch[n];
    if (g != cur) {
      if (cur >= 0) atomicAdd(&emb[(size_t)cur * 128 + d], acc);
      cur = g; acc = 0.f;
    }
    acc += h[(size_t)n * 128 + d];
  }
  if (cur >= 0) atomicAdd(&emb[(size_t)cur * 128 + d], acc);
}

// ---------------- final score ----------------
__global__ __launch_bounds__(128) void score_kernel(
    const float* __restrict__ hemb, const float* __restrict__ temb,
    const int* __restrict__ rels,
    const float* __restrict__ wqW, const float* __restrict__ wqb,
    const float* __restrict__ wkW, const float* __restrict__ wkb,
    const float* __restrict__ rel_emb, float* __restrict__ out)
{
  const int b = blockIdx.x, i = threadIdx.x;
  __shared__ float hs[128], ts[128], hnv[128], tnv[128], red[128];
  hs[i] = hemb[(size_t)b * 128 + i];
  ts[i] = temb[(size_t)b * 128 + i];
  __syncthreads();
  float qv = wqb[i], kv = wkb[i];
  for (int k = 0; k < 128; k++) {
    qv += hs[k] * wqW[k * 128 + i];
    kv += ts[k] * wkW[k * 128 + i];
  }
  float inter = tanhf(qv * kv);
  float hx = hs[i] + inter, tx2 = ts[i] + inter;

  red[i] = hx * hx; __syncthreads();
  for (int s = 64; s > 0; s >>= 1) { if (i < s) red[i] += red[i + s]; __syncthreads(); }
  float hnorm = fmaxf(sqrtf(red[0]), 1e-12f);
  __syncthreads();
  red[i] = tx2 * tx2; __syncthreads();
  for (int s = 64; s > 0; s >>= 1) { if (i < s) red[i] += red[i + s]; __syncthreads(); }
  float tnorm = fmaxf(sqrtf(red[0]), 1e-12f);
  __syncthreads();
  hnv[i] = hx / hnorm; tnv[i] = tx2 / tnorm;
  __syncthreads();

  const float* R = rel_emb + (size_t)rels[b] * 16384 + (size_t)i * 128;
  float dot = 0.f, nrm = 0.f;
  for (int j = 0; j < 128; j++) { float r = R[j]; dot += r * tnv[j]; nrm += r * r; }
  float contrib = hnv[i] * dot / fmaxf(sqrtf(nrm), 1e-12f);
  red[i] = contrib; __syncthreads();
  for (int s = 64; s > 0; s >>= 1) { if (i < s) red[i] += red[i + s]; __syncthreads(); }
  if (i == 0) out[b] = red[0];
}

extern "C" void kernel_launch(void* const* d_in, const int* in_sizes, int n_in,
                              void* d_out, int out_size, void* d_ws, size_t ws_size,
                              hipStream_t stream)
{
  const float* h_x     = (const float*)d_in[0];
  const int*   h_ei    = (const int*)d_in[1];
  const int*   h_batch = (const int*)d_in[2];
  const float* t_x     = (const float*)d_in[3];
  const int*   t_ei    = (const int*)d_in[4];
  const int*   t_batch = (const int*)d_in[5];
  const int*   rels    = (const int*)d_in[6];
  const float* lin0_W  = (const float*)d_in[7];
  const float* lin0_b  = (const float*)d_in[8];
  const float* Wq      = (const float*)d_in[9];
  const float* bq      = (const float*)d_in[10];
  const float* Wk      = (const float*)d_in[11];
  const float* bk      = (const float*)d_in[12];
  const float* Wv      = (const float*)d_in[13];
  const float* bv      = (const float*)d_in[14];
  const float* Ws      = (const float*)d_in[15];
  const float* bs      = (const float*)d_in[16];
  const float* wqW     = (const float*)d_in[17];
  const float* wqb     = (const float*)d_in[18];
  const float* wkW     = (const float*)d_in[19];
  const float* wkb     = (const float*)d_in[20];
  const float* rel_emb = (const float*)d_in[21];

  const int N = in_sizes[2];          // 50000
  const int E = in_sizes[1] / 2;      // 400000
  const int G = in_sizes[6];          // 512
  const int inF = in_sizes[7] / 128;  // 70

  char* ws = (char*)d_ws;
  size_t off = 0;
  auto alloc = [&](size_t bytes) -> void* {
    void* p = ws + off; off += (bytes + 255) & ~(size_t)255; return p;
  };
  float* hA            = (float*)alloc((size_t)N * 128 * 4);
  float* hB            = (float*)alloc((size_t)N * 128 * 4);
  unsigned short* qb   = (unsigned short*)alloc((size_t)N * 512 * 2);
  unsigned short* kbuf = (unsigned short*)alloc((size_t)N * 512 * 2);
  unsigned short* vbuf = (unsigned short*)alloc((size_t)N * 512 * 2);
  float* ebuf          = (float*)alloc((size_t)E * 4 * 4);
  float* den           = (float*)alloc((size_t)N * 4 * 4);
  float* hEmb          = (float*)alloc((size_t)G * 128 * 4);
  float* tEmb          = (float*)alloc((size_t)G * 128 * 4);
  (void)ws_size; (void)n_in; (void)out_size;

  for (int g = 0; g < 2; g++) {
    const float* x     = g ? t_x : h_x;
    const int*   ei    = g ? t_ei : h_ei;
    const int*   batch = g ? t_batch : h_batch;
    float*       emb   = g ? tEmb : hEmb;
    const int* srcp = ei;
    const int* dstp = ei + E;

    lin0_kernel<<<N, 128, 0, stream>>>(x, lin0_W, lin0_b, hA, N, inF);
    float* cur = hA; float* nxt = hB;
    for (int l = 0; l < 3; l++) {
      hipMemsetAsync(den, 0, (size_t)N * 4 * 4, stream);
      dim3 pg((N + 63) / 64, 26);
      proj_kernel<<<pg, 256, 0, stream>>>(cur, N,
          Wq + (size_t)l * 65536, bq + (size_t)l * 512,
          Wk + (size_t)l * 65536, bk + (size_t)l * 512,
          Wv + (size_t)l * 65536, bv + (size_t)l * 512,
          Ws + (size_t)l * 16384, bs + (size_t)l * 128,
          qb, kbuf, vbuf, nxt);
      int eb = (E + 3) / 4;
      edge_alpha_kernel<<<eb, 256, 0, stream>>>(qb, kbuf, srcp, dstp, ebuf, den, E);
      edge_aggr_kernel<<<eb, 256, 0, stream>>>(vbuf, ebuf, den, srcp, dstp, nxt, E);
      int rn = N * 128;
      relu_kernel<<<(rn + 255) / 256, 256, 0, stream>>>(nxt, rn);
      float* tmp = cur; cur = nxt; nxt = tmp;
    }
    hipMemsetAsync(emb, 0, (size_t)G * 128 * 4, stream);
    pool_kernel<<<(N + 127) / 128, 128, 0, stream>>>(cur, batch, emb, N);
  }

  score_kernel<<<G, 128, 0, stream>>>(hEmb, tEmb, rels, wqW, wqb, wkW, wkb,
                                      rel_emb, (float*)d_out);
}

// Round 2
// 2992.430 us; speedup vs baseline: 1.6479x; 1.6479x over previous
//
#include <hip/hip_runtime.h>
#include <math.h>

#define HID 128

__device__ __forceinline__ float bf2f(unsigned int u16) {
  union { unsigned int i; float f; } x; x.i = u16 << 16; return x.f;
}
__device__ __forceinline__ unsigned short f2bf(float f) {
  union { float f; unsigned int i; } x; x.f = f;
  unsigned int i = x.i;
  unsigned int r = i + 0x7FFFu + ((i >> 16) & 1u);
  return (unsigned short)(r >> 16);
}

// ---------------- lin0: h = x @ W(70x128) + b ----------------
__global__ __launch_bounds__(128) void lin0_kernel(
    const float* __restrict__ x, const float* __restrict__ W,
    const float* __restrict__ b, float* __restrict__ h, int N, int inF)
{
  __shared__ float xs[128];
  int n = blockIdx.x;
  int t = threadIdx.x;
  if (t < inF) xs[t] = x[(size_t)n * inF + t];
  __syncthreads();
  float acc = b[t];
  for (int k = 0; k < inF; k++) acc += xs[k] * W[(size_t)k * 128 + t];
  h[(size_t)n * 128 + t] = acc;
}

// ---------------- fused projection GEMM ----------------
// A[M,128] fp32.  Output cols: [0,512)=q, [512,1024)=k, [1024,1536)=v (bf16),
// [1536,1664)=skip -> hnext (fp32).  BM=64, BN=64, BK=16, 256 threads.
__global__ __launch_bounds__(256) void proj_kernel(
    const float* __restrict__ A, int M,
    const float* __restrict__ Wq, const float* __restrict__ bq,
    const float* __restrict__ Wk, const float* __restrict__ bk,
    const float* __restrict__ Wv, const float* __restrict__ bv,
    const float* __restrict__ Ws, const float* __restrict__ bs,
    unsigned short* __restrict__ qo, unsigned short* __restrict__ ko,
    unsigned short* __restrict__ vo, float* __restrict__ hn)
{
  __shared__ float As[16][64];
  __shared__ float Bs[16][64];
  const int t = threadIdx.x;
  const int m0 = blockIdx.x * 64;
  const int n0 = blockIdx.y * 64;
  const int region = n0 >> 9;                 // 0=q 1=k 2=v 3=skip
  const float* B; const float* bias; int ldb;
  if (region == 0)      { B = Wq; bias = bq; ldb = 512; }
  else if (region == 1) { B = Wk; bias = bk; ldb = 512; }
  else if (region == 2) { B = Wv; bias = bv; ldb = 512; }
  else                  { B = Ws; bias = bs; ldb = 128; }
  const int cl = n0 - region * 512;           // local col base within matrix

  const int am = t >> 2;                      // 0..63
  const int ak = (t & 3) * 4;                 // 0,4,8,12
  const int bkr = t >> 4;                     // 0..15
  const int bn  = (t & 15) * 4;               // 0..60
  const int tx = t & 15, ty = t >> 4;

  const int arow = m0 + am;
  const bool avalid = arow < M;
  const float* Aptr = A + (size_t)arow * 128;

  float acc[4][4];
#pragma unroll
  for (int i = 0; i < 4; i++)
#pragma unroll
    for (int j = 0; j < 4; j++) acc[i][j] = 0.f;

  for (int k0 = 0; k0 < 128; k0 += 16) {
    float4 av = avalid ? *(const float4*)(Aptr + k0 + ak) : make_float4(0.f,0.f,0.f,0.f);
    float4 bv4 = *(const float4*)(B + (size_t)(k0 + bkr) * ldb + cl + bn);
    __syncthreads();   // protect LDS from previous iteration's readers
    As[ak+0][am] = av.x; As[ak+1][am] = av.y; As[ak+2][am] = av.z; As[ak+3][am] = av.w;
    *(float4*)(&Bs[bkr][bn]) = bv4;
    __syncthreads();
#pragma unroll
    for (int kk = 0; kk < 16; kk++) {
      const float4 a  = *(const float4*)(&As[kk][ty*4]);
      const float4 bb = *(const float4*)(&Bs[kk][tx*4]);
      acc[0][0] += a.x*bb.x; acc[0][1] += a.x*bb.y; acc[0][2] += a.x*bb.z; acc[0][3] += a.x*bb.w;
      acc[1][0] += a.y*bb.x; acc[1][1] += a.y*bb.y; acc[1][2] += a.y*bb.z; acc[1][3] += a.y*bb.w;
      acc[2][0] += a.z*bb.x; acc[2][1] += a.z*bb.y; acc[2][2] += a.z*bb.z; acc[2][3] += a.z*bb.w;
      acc[3][0] += a.w*bb.x; acc[3][1] += a.w*bb.y; acc[3][2] += a.w*bb.z; acc[3][3] += a.w*bb.w;
    }
  }

#pragma unroll
  for (int ii = 0; ii < 4; ii++) {
    int row = m0 + ty*4 + ii;
    if (row >= M) continue;
#pragma unroll
    for (int jj = 0; jj < 4; jj++) {
      int col = cl + tx*4 + jj;
      float val = acc[ii][jj] + bias[col];
      if (region == 0)      qo[(size_t)row*512 + col] = f2bf(val);
      else if (region == 1) ko[(size_t)row*512 + col] = f2bf(val);
      else if (region == 2) vo[(size_t)row*512 + col] = f2bf(val);
      else                  hn[(size_t)row*128 + col] = val;
    }
  }
}

// ---------------- CSR build ----------------
__global__ __launch_bounds__(256) void hist_kernel(
    const int* __restrict__ dst, int* __restrict__ deg, int E)
{
  int e = blockIdx.x * 256 + threadIdx.x;
  if (e < E) atomicAdd(&deg[dst[e]], 1);
}

// exclusive scan of 256-chunks; bsums gets each block's total (may be null)
__global__ __launch_bounds__(256) void scan_block_kernel(
    const int* __restrict__ in, int* __restrict__ out, int* __restrict__ bsums, int N)
{
  __shared__ int sm[256];
  int i = blockIdx.x * 256 + threadIdx.x;
  int v = (i < N) ? in[i] : 0;
  sm[threadIdx.x] = v; __syncthreads();
  for (int off = 1; off < 256; off <<= 1) {
    int t = (threadIdx.x >= off) ? sm[threadIdx.x - off] : 0;
    __syncthreads();
    sm[threadIdx.x] += t;
    __syncthreads();
  }
  if (i < N) out[i] = sm[threadIdx.x] - v;   // exclusive
  if (threadIdx.x == 255 && bsums) bsums[blockIdx.x] = sm[255];
}

__global__ __launch_bounds__(256) void scan_finish_kernel(
    int* __restrict__ row_start, int* __restrict__ cursor,
    const int* __restrict__ bsums_scan, int N, int E)
{
  int i = blockIdx.x * 256 + threadIdx.x;
  if (i < N) {
    int val = row_start[i] + bsums_scan[blockIdx.x];
    row_start[i] = val;
    cursor[i] = val;
  }
  if (i == 0) row_start[N] = E;
}

__global__ __launch_bounds__(256) void scatter_kernel(
    const int* __restrict__ src, const int* __restrict__ dst,
    int* __restrict__ cursor, int* __restrict__ csr_src, int E)
{
  int e = blockIdx.x * 256 + threadIdx.x;
  if (e < E) {
    int pos = atomicAdd(&cursor[dst[e]], 1);
    csr_src[pos] = src[e];
  }
}

// ---------------- fused per-node attention (one wave per dst node) ----------
// hn[d] = relu(hn[d] + mean_h( sum_e a_eh * v[src_e,h,:] ))
__global__ __launch_bounds__(256) void node_attn_kernel(
    const unsigned short* __restrict__ q, const unsigned short* __restrict__ k,
    const unsigned short* __restrict__ v,
    const int* __restrict__ row_start, const int* __restrict__ csr_src,
    float* __restrict__ hn, int N)
{
  int d = (blockIdx.x * 256 + threadIdx.x) >> 6;
  int lane = threadIdx.x & 63;
  if (d >= N) return;
  int beg = row_start[d], end = row_start[d + 1];

  const uint4 qv = *(const uint4*)(q + (size_t)d * 512 + lane * 8);
  float q0 = bf2f(qv.x & 0xFFFFu), q1 = bf2f(qv.x >> 16);
  float q2 = bf2f(qv.y & 0xFFFFu), q3 = bf2f(qv.y >> 16);
  float q4 = bf2f(qv.z & 0xFFFFu), q5 = bf2f(qv.z >> 16);
  float q6 = bf2f(qv.w & 0xFFFFu), q7 = bf2f(qv.w >> 16);

  float num[8] = {0.f,0.f,0.f,0.f,0.f,0.f,0.f,0.f};
  float den = 0.f;
  for (int i = beg; i < end; i++) {
    int s = csr_src[i];
    const uint4 kv = *(const uint4*)(k + (size_t)s * 512 + lane * 8);
    const uint4 vv = *(const uint4*)(v + (size_t)s * 512 + lane * 8);
    float p = q0 * bf2f(kv.x & 0xFFFFu) + q1 * bf2f(kv.x >> 16)
            + q2 * bf2f(kv.y & 0xFFFFu) + q3 * bf2f(kv.y >> 16)
            + q4 * bf2f(kv.z & 0xFFFFu) + q5 * bf2f(kv.z >> 16)
            + q6 * bf2f(kv.w & 0xFFFFu) + q7 * bf2f(kv.w >> 16);
    p += __shfl_xor(p, 1);
    p += __shfl_xor(p, 2);
    p += __shfl_xor(p, 4);
    p += __shfl_xor(p, 8);
    float e = __expf(p * 0.08838834764831845f);  // 1/sqrt(128)
    den += e;
    num[0] += e * bf2f(vv.x & 0xFFFFu); num[1] += e * bf2f(vv.x >> 16);
    num[2] += e * bf2f(vv.y & 0xFFFFu); num[3] += e * bf2f(vv.y >> 16);
    num[4] += e * bf2f(vv.z & 0xFFFFu); num[5] += e * bf2f(vv.z >> 16);
    num[6] += e * bf2f(vv.w & 0xFFFFu); num[7] += e * bf2f(vv.w >> 16);
  }
  // per-head normalize (lane's head) + 1/4 for mean over heads
  float inv = (den > 0.f) ? 0.25f / den : 0.f;
#pragma unroll
  for (int j = 0; j < 8; j++) {
    float r = num[j] * inv;
    r += __shfl_xor(r, 16);   // combine the 4 heads (lanes L, L^16, L^32, L^48)
    r += __shfl_xor(r, 32);
    num[j] = r;
  }
  if (lane < 16) {
    float* hp = hn + (size_t)d * 128 + lane * 8;
    float4 o0 = *(const float4*)(hp);
    float4 o1 = *(const float4*)(hp + 4);
    o0.x = fmaxf(o0.x + num[0], 0.f);
    o0.y = fmaxf(o0.y + num[1], 0.f);
    o0.z = fmaxf(o0.z + num[2], 0.f);
    o0.w = fmaxf(o0.w + num[3], 0.f);
    o1.x = fmaxf(o1.x + num[4], 0.f);
    o1.y = fmaxf(o1.y + num[5], 0.f);
    o1.z = fmaxf(o1.z + num[6], 0.f);
    o1.w = fmaxf(o1.w + num[7], 0.f);
    *(float4*)(hp) = o0;
    *(float4*)(hp + 4) = o1;
  }
}

// ---------------- pooling: emb[batch[n]] += h[n] (batch sorted) ----------------
__global__ __launch_bounds__(128) void pool_kernel(
    const float* __restrict__ h, const int* __restrict__ batch,
    float* __restrict__ emb, int N)
{
  int d = threadIdx.x;
  int n0 = blockIdx.x * 128;
  int n1 = min(n0 + 128, N);
  float acc = 0.f; int cur = -1;
  for (int n = n0; n < n1; n++) {
    int g = batch[n];
    if (g != cur) {
      if (cur >= 0) atomicAdd(&emb[(size_t)cur * 128 + d], acc);
      cur = g; acc = 0.f;
    }
    acc += h[(size_t)n * 128 + d];
  }
  if (cur >= 0) atomicAdd(&emb[(size_t)cur * 128 + d], acc);
}

// ---------------- final score ----------------
__global__ __launch_bounds__(128) void score_kernel(
    const float* __restrict__ hemb, const float* __restrict__ temb,
    const int* __restrict__ rels,
    const float* __restrict__ wqW, const float* __restrict__ wqb,
    const float* __restrict__ wkW, const float* __restrict__ wkb,
    const float* __restrict__ rel_emb, float* __restrict__ out)
{
  const int b = blockIdx.x, i = threadIdx.x;
  __shared__ float hs[128], ts[128], hnv[128], tnv[128], red[128];
  hs[i] = hemb[(size_t)b * 128 + i];
  ts[i] = temb[(size_t)b * 128 + i];
  __syncthreads();
  float qv = wqb[i], kv = wkb[i];
  for (int k = 0; k < 128; k++) {
    qv += hs[k] * wqW[k * 128 + i];
    kv += ts[k] * wkW[k * 128 + i];
  }
  float inter = tanhf(qv * kv);
  float hx = hs[i] + inter, tx2 = ts[i] + inter;

  red[i] = hx * hx; __syncthreads();
  for (int s = 64; s > 0; s >>= 1) { if (i < s) red[i] += red[i + s]; __syncthreads(); }
  float hnorm = fmaxf(sqrtf(red[0]), 1e-12f);
  __syncthreads();
  red[i] = tx2 * tx2; __syncthreads();
  for (int s = 64; s > 0; s >>= 1) { if (i < s) red[i] += red[i + s]; __syncthreads(); }
  float tnorm = fmaxf(sqrtf(red[0]), 1e-12f);
  __syncthreads();
  hnv[i] = hx / hnorm; tnv[i] = tx2 / tnorm;
  __syncthreads();

  const float* R = rel_emb + (size_t)rels[b] * 16384 + (size_t)i * 128;
  float dot = 0.f, nrm = 0.f;
  for (int j = 0; j < 128; j++) { float r = R[j]; dot += r * tnv[j]; nrm += r * r; }
  float contrib = hnv[i] * dot / fmaxf(sqrtf(nrm), 1e-12f);
  red[i] = contrib; __syncthreads();
  for (int s = 64; s > 0; s >>= 1) { if (i < s) red[i] += red[i + s]; __syncthreads(); }
  if (i == 0) out[b] = red[0];
}

extern "C" void kernel_launch(void* const* d_in, const int* in_sizes, int n_in,
                              void* d_out, int out_size, void* d_ws, size_t ws_size,
                              hipStream_t stream)
{
  const float* h_x     = (const float*)d_in[0];
  const int*   h_ei    = (const int*)d_in[1];
  const int*   h_batch = (const int*)d_in[2];
  const float* t_x     = (const float*)d_in[3];
  const int*   t_ei    = (const int*)d_in[4];
  const int*   t_batch = (const int*)d_in[5];
  const int*   rels    = (const int*)d_in[6];
  const float* lin0_W  = (const float*)d_in[7];
  const float* lin0_b  = (const float*)d_in[8];
  const float* Wq      = (const float*)d_in[9];
  const float* bq      = (const float*)d_in[10];
  const float* Wk      = (const float*)d_in[11];
  const float* bk      = (const float*)d_in[12];
  const float* Wv      = (const float*)d_in[13];
  const float* bv      = (const float*)d_in[14];
  const float* Ws      = (const float*)d_in[15];
  const float* bs      = (const float*)d_in[16];
  const float* wqW     = (const float*)d_in[17];
  const float* wqb     = (const float*)d_in[18];
  const float* wkW     = (const float*)d_in[19];
  const float* wkb     = (const float*)d_in[20];
  const float* rel_emb = (const float*)d_in[21];

  const int N = in_sizes[2];          // 50000
  const int E = in_sizes[1] / 2;      // 400000
  const int G = in_sizes[6];          // 512
  const int inF = in_sizes[7] / 128;  // 70

  char* ws = (char*)d_ws;
  size_t off = 0;
  auto alloc = [&](size_t bytes) -> void* {
    void* p = ws + off; off += (bytes + 255) & ~(size_t)255; return p;
  };
  float* hA            = (float*)alloc((size_t)N * 128 * 4);
  float* hB            = (float*)alloc((size_t)N * 128 * 4);
  unsigned short* qb   = (unsigned short*)alloc((size_t)N * 512 * 2);
  unsigned short* kbuf = (unsigned short*)alloc((size_t)N * 512 * 2);
  unsigned short* vbuf = (unsigned short*)alloc((size_t)N * 512 * 2);
  int* deg             = (int*)alloc((size_t)(N + 1) * 4);
  int* row_start       = (int*)alloc((size_t)(N + 1) * 4);
  int* cursor          = (int*)alloc((size_t)(N + 1) * 4);
  int* bsums           = (int*)alloc((size_t)1024 * 4);
  int* bsums_scan      = (int*)alloc((size_t)1024 * 4);
  int* csr_src         = (int*)alloc((size_t)E * 4);
  float* hEmb          = (float*)alloc((size_t)G * 128 * 4);
  float* tEmb          = (float*)alloc((size_t)G * 128 * 4);
  (void)ws_size; (void)n_in; (void)out_size;

  const int nScanBlocks = (N + 255) / 256;   // 196 <= 256

  for (int g = 0; g < 2; g++) {
    const float* x     = g ? t_x : h_x;
    const int*   ei    = g ? t_ei : h_ei;
    const int*   batch = g ? t_batch : h_batch;
    float*       emb   = g ? tEmb : hEmb;
    const int* srcp = ei;
    const int* dstp = ei + E;

    // --- build CSR (edges grouped by dst) ---
    hipMemsetAsync(deg, 0, (size_t)(N + 1) * 4, stream);
    hist_kernel<<<(E + 255) / 256, 256, 0, stream>>>(dstp, deg, E);
    scan_block_kernel<<<nScanBlocks, 256, 0, stream>>>(deg, row_start, bsums, N);
    scan_block_kernel<<<1, 256, 0, stream>>>(bsums, bsums_scan, nullptr, nScanBlocks);
    scan_finish_kernel<<<nScanBlocks, 256, 0, stream>>>(row_start, cursor, bsums_scan, N, E);
    scatter_kernel<<<(E + 255) / 256, 256, 0, stream>>>(srcp, dstp, cursor, csr_src, E);

    lin0_kernel<<<N, 128, 0, stream>>>(x, lin0_W, lin0_b, hA, N, inF);
    float* cur = hA; float* nxt = hB;
    for (int l = 0; l < 3; l++) {
      dim3 pg((N + 63) / 64, 26);
      proj_kernel<<<pg, 256, 0, stream>>>(cur, N,
          Wq + (size_t)l * 65536, bq + (size_t)l * 512,
          Wk + (size_t)l * 65536, bk + (size_t)l * 512,
          Wv + (size_t)l * 65536, bv + (size_t)l * 512,
          Ws + (size_t)l * 16384, bs + (size_t)l * 128,
          qb, kbuf, vbuf, nxt);
      node_attn_kernel<<<(N + 3) / 4, 256, 0, stream>>>(qb, kbuf, vbuf,
          row_start, csr_src, nxt, N);
      float* tmp = cur; cur = nxt; nxt = tmp;
    }
    hipMemsetAsync(emb, 0, (size_t)G * 128 * 4, stream);
    pool_kernel<<<(N + 127) / 128, 128, 0, stream>>>(cur, batch, emb, N);
  }

  score_kernel<<<G, 128, 0, stream>>>(hEmb, tEmb, rels, wqW, wqb, wkW, wkb,
                                      rel_emb, (float*)d_out);
}

// Round 3
// 1875.797 us; speedup vs baseline: 2.6289x; 1.5953x over previous
//
#include <hip/hip_runtime.h>
#include <math.h>

#define HID 128

typedef __attribute__((ext_vector_type(8))) short short8;
typedef __attribute__((ext_vector_type(4))) float f32x4;

__device__ __forceinline__ float bf2f(unsigned int u16) {
  union { unsigned int i; float f; } x; x.i = u16 << 16; return x.f;
}
__device__ __forceinline__ unsigned short f2bf(float f) {
  union { float f; unsigned int i; } x; x.f = f;
  unsigned int i = x.i;
  unsigned int r = i + 0x7FFFu + ((i >> 16) & 1u);
  return (unsigned short)(r >> 16);
}

// ---------------- weight convert: BT[l][n][k] = W[l][k][n] (bf16), biascat ----
__global__ __launch_bounds__(128) void wcvt_kernel(
    const float* __restrict__ Wq, const float* __restrict__ bq,
    const float* __restrict__ Wk, const float* __restrict__ bk,
    const float* __restrict__ Wv, const float* __restrict__ bv,
    const float* __restrict__ Ws, const float* __restrict__ bs,
    unsigned short* __restrict__ BT, float* __restrict__ biascat)
{
  int id = blockIdx.x;
  int l = id / 1664;
  int n = id - l * 1664;
  int k = threadIdx.x;
  const float* W; const float* bias; int nl, ldb;
  if (n < 512)       { W = Wq + (size_t)l * 65536; bias = bq + (size_t)l * 512; nl = n;        ldb = 512; }
  else if (n < 1024) { W = Wk + (size_t)l * 65536; bias = bk + (size_t)l * 512; nl = n - 512;  ldb = 512; }
  else if (n < 1536) { W = Wv + (size_t)l * 65536; bias = bv + (size_t)l * 512; nl = n - 1024; ldb = 512; }
  else               { W = Ws + (size_t)l * 16384; bias = bs + (size_t)l * 128; nl = n - 1536; ldb = 128; }
  BT[((size_t)l * 1664 + n) * 128 + k] = f2bf(W[(size_t)k * ldb + nl]);
  if (k == 0) biascat[(size_t)l * 1664 + n] = bias[nl];
}

// ---------------- lin0: h = x @ W(70x128) + b  (fp32 + bf16 copy) ------------
__global__ __launch_bounds__(128) void lin0_kernel(
    const float* __restrict__ x, const float* __restrict__ W,
    const float* __restrict__ b, float* __restrict__ h,
    unsigned short* __restrict__ hb, int N, int inF)
{
  __shared__ float xs[128];
  int n = blockIdx.x;
  int t = threadIdx.x;
  if (t < inF) xs[t] = x[(size_t)n * inF + t];
  __syncthreads();
  float acc = b[t];
  for (int k = 0; k < inF; k++) acc += xs[k] * W[(size_t)k * 128 + t];
  h[(size_t)n * 128 + t] = acc;
  hb[(size_t)n * 128 + t] = f2bf(acc);
}

// ---------------- MFMA projection GEMM ----------------
// C[M,1664] = A[M,128](bf16) @ BT^T ; cols [0,512)q [512,1024)k [1024,1536)v
// (bf16 out), [1536,1664) skip -> hn (fp32). 128x128 tile, BK=32, 4 waves.
__global__ __launch_bounds__(256) void proj_mfma_kernel(
    const unsigned short* __restrict__ A, const unsigned short* __restrict__ BT,
    const float* __restrict__ bias, int M,
    unsigned short* __restrict__ qo, unsigned short* __restrict__ ko,
    unsigned short* __restrict__ vo, float* __restrict__ hn)
{
  __shared__ unsigned short lsA[128 * 32];
  __shared__ unsigned short lsB[128 * 32];
  const int t = threadIdx.x;
  const int wv = t >> 6, ln = t & 63;
  const int wx = wv & 1, wy = wv >> 1;
  const int m0 = blockIdx.x * 128;
  const int n0 = blockIdx.y * 128;
  const int region = n0 >> 9;                       // 0=q 1=k 2=v 3=skip
  unsigned short* out16 = (region == 0) ? qo : (region == 1) ? ko : vo;
  const int creg = region * 512;

  f32x4 acc[4][4];
#pragma unroll
  for (int i = 0; i < 4; i++)
#pragma unroll
    for (int j = 0; j < 4; j++) acc[i][j] = (f32x4){0.f, 0.f, 0.f, 0.f};

  const int fr = ln & 15;
  const int fk = (ln >> 4) * 8;

  for (int kb = 0; kb < 4; kb++) {
    __syncthreads();
#pragma unroll
    for (int j = 0; j < 2; j++) {
      const int c = j * 256 + wv * 64 + ln;         // chunk id (16B each)
      const int rA = c >> 2;
      const int kq = (c & 3) * 8;
      int grA = m0 + rA; if (grA >= M) grA = M - 1; // clamp for tail tile
      const unsigned short* gA = A + (size_t)grA * 128 + kb * 32 + kq;
      const unsigned short* gB = BT + (size_t)(n0 + rA) * 128 + kb * 32 + kq;
      const int lbase = (j * 256 + wv * 64) * 16;   // wave-uniform LDS byte base
      __builtin_amdgcn_global_load_lds(
          (const __attribute__((address_space(1))) void*)gA,
          (__attribute__((address_space(3))) void*)((char*)lsA + lbase), 16, 0, 0);
      __builtin_amdgcn_global_load_lds(
          (const __attribute__((address_space(1))) void*)gB,
          (__attribute__((address_space(3))) void*)((char*)lsB + lbase), 16, 0, 0);
    }
    __syncthreads();
    short8 af[4], bfr[4];
#pragma unroll
    for (int i = 0; i < 4; i++)
      af[i] = *(const short8*)(&lsA[(wy * 64 + i * 16 + fr) * 32 + fk]);
#pragma unroll
    for (int j = 0; j < 4; j++)
      bfr[j] = *(const short8*)(&lsB[(wx * 64 + j * 16 + fr) * 32 + fk]);
#pragma unroll
    for (int i = 0; i < 4; i++)
#pragma unroll
      for (int j = 0; j < 4; j++)
        acc[i][j] = __builtin_amdgcn_mfma_f32_16x16x32_bf16(af[i], bfr[j], acc[i][j], 0, 0, 0);
  }

  const int rbase = (ln >> 4) * 4;
  const int cl = ln & 15;
#pragma unroll
  for (int j = 0; j < 4; j++) {
    const int colg = n0 + wx * 64 + j * 16 + cl;    // global col in [0,1664)
    const float bv = bias[colg];
    const int col = colg - creg;                    // local col within region
#pragma unroll
    for (int i = 0; i < 4; i++) {
      f32x4 c = acc[i][j];
#pragma unroll
      for (int r = 0; r < 4; r++) {
        const int row = m0 + wy * 64 + i * 16 + rbase + r;
        if (row < M) {
          float val = c[r] + bv;
          if (region < 3) out16[(size_t)row * 512 + col] = f2bf(val);
          else            hn[(size_t)row * 128 + col] = val;
        }
      }
    }
  }
}

// ---------------- CSR build ----------------
__global__ __launch_bounds__(256) void hist_kernel(
    const int* __restrict__ dst, int* __restrict__ deg, int E)
{
  int e = blockIdx.x * 256 + threadIdx.x;
  if (e < E) atomicAdd(&deg[dst[e]], 1);
}

__global__ __launch_bounds__(256) void scan_block_kernel(
    const int* __restrict__ in, int* __restrict__ out, int* __restrict__ bsums, int N)
{
  __shared__ int sm[256];
  int i = blockIdx.x * 256 + threadIdx.x;
  int v = (i < N) ? in[i] : 0;
  sm[threadIdx.x] = v; __syncthreads();
  for (int off = 1; off < 256; off <<= 1) {
    int t = (threadIdx.x >= off) ? sm[threadIdx.x - off] : 0;
    __syncthreads();
    sm[threadIdx.x] += t;
    __syncthreads();
  }
  if (i < N) out[i] = sm[threadIdx.x] - v;   // exclusive
  if (threadIdx.x == 255 && bsums) bsums[blockIdx.x] = sm[255];
}

__global__ __launch_bounds__(256) void scan_finish_kernel(
    int* __restrict__ row_start, int* __restrict__ cursor,
    const int* __restrict__ bsums_scan, int N, int E)
{
  int i = blockIdx.x * 256 + threadIdx.x;
  if (i < N) {
    int val = row_start[i] + bsums_scan[blockIdx.x];
    row_start[i] = val;
    cursor[i] = val;
  }
  if (i == 0) row_start[N] = E;
}

__global__ __launch_bounds__(256) void scatter_kernel(
    const int* __restrict__ src, const int* __restrict__ dst,
    int* __restrict__ cursor, int* __restrict__ csr_src, int E)
{
  int e = blockIdx.x * 256 + threadIdx.x;
  if (e < E) {
    int pos = atomicAdd(&cursor[dst[e]], 1);
    csr_src[pos] = src[e];
  }
}

// ---------------- fused per-node attention (one wave per dst node) ----------
// h[d] = relu(h[d] + mean_h( softmax_e * v[src_e,h,:] ));  hb = bf16(h)
__global__ __launch_bounds__(256) void node_attn_kernel(
    const unsigned short* __restrict__ q, const unsigned short* __restrict__ k,
    const unsigned short* __restrict__ v,
    const int* __restrict__ row_start, const int* __restrict__ csr_src,
    float* __restrict__ hn, unsigned short* __restrict__ hb, int N)
{
  int d = (blockIdx.x * 256 + threadIdx.x) >> 6;
  int lane = threadIdx.x & 63;
  if (d >= N) return;
  int beg = row_start[d], end = row_start[d + 1];

  const uint4 qv = *(const uint4*)(q + (size_t)d * 512 + lane * 8);
  float q0 = bf2f(qv.x & 0xFFFFu), q1 = bf2f(qv.x >> 16);
  float q2 = bf2f(qv.y & 0xFFFFu), q3 = bf2f(qv.y >> 16);
  float q4 = bf2f(qv.z & 0xFFFFu), q5 = bf2f(qv.z >> 16);
  float q6 = bf2f(qv.w & 0xFFFFu), q7 = bf2f(qv.w >> 16);

  float num[8] = {0.f,0.f,0.f,0.f,0.f,0.f,0.f,0.f};
  float den = 0.f;
  for (int i = beg; i < end; i++) {
    int s = csr_src[i];
    const uint4 kv = *(const uint4*)(k + (size_t)s * 512 + lane * 8);
    const uint4 vv = *(const uint4*)(v + (size_t)s * 512 + lane * 8);
    float p = q0 * bf2f(kv.x & 0xFFFFu) + q1 * bf2f(kv.x >> 16)
            + q2 * bf2f(kv.y & 0xFFFFu) + q3 * bf2f(kv.y >> 16)
            + q4 * bf2f(kv.z & 0xFFFFu) + q5 * bf2f(kv.z >> 16)
            + q6 * bf2f(kv.w & 0xFFFFu) + q7 * bf2f(kv.w >> 16);
    p += __shfl_xor(p, 1);
    p += __shfl_xor(p, 2);
    p += __shfl_xor(p, 4);
    p += __shfl_xor(p, 8);
    float e = __expf(p * 0.08838834764831845f);  // 1/sqrt(128)
    den += e;
    num[0] += e * bf2f(vv.x & 0xFFFFu); num[1] += e * bf2f(vv.x >> 16);
    num[2] += e * bf2f(vv.y & 0xFFFFu); num[3] += e * bf2f(vv.y >> 16);
    num[4] += e * bf2f(vv.z & 0xFFFFu); num[5] += e * bf2f(vv.z >> 16);
    num[6] += e * bf2f(vv.w & 0xFFFFu); num[7] += e * bf2f(vv.w >> 16);
  }
  float inv = (den > 0.f) ? 0.25f / den : 0.f;
#pragma unroll
  for (int j = 0; j < 8; j++) {
    float r = num[j] * inv;
    r += __shfl_xor(r, 16);   // combine 4 heads
    r += __shfl_xor(r, 32);
    num[j] = r;
  }
  if (lane < 16) {
    float* hp = hn + (size_t)d * 128 + lane * 8;
    float4 o0 = *(const float4*)(hp);
    float4 o1 = *(const float4*)(hp + 4);
    o0.x = fmaxf(o0.x + num[0], 0.f);
    o0.y = fmaxf(o0.y + num[1], 0.f);
    o0.z = fmaxf(o0.z + num[2], 0.f);
    o0.w = fmaxf(o0.w + num[3], 0.f);
    o1.x = fmaxf(o1.x + num[4], 0.f);
    o1.y = fmaxf(o1.y + num[5], 0.f);
    o1.z = fmaxf(o1.z + num[6], 0.f);
    o1.w = fmaxf(o1.w + num[7], 0.f);
    *(float4*)(hp) = o0;
    *(float4*)(hp + 4) = o1;
    uint4 hv;
    hv.x = (unsigned int)f2bf(o0.x) | ((unsigned int)f2bf(o0.y) << 16);
    hv.y = (unsigned int)f2bf(o0.z) | ((unsigned int)f2bf(o0.w) << 16);
    hv.z = (unsigned int)f2bf(o1.x) | ((unsigned int)f2bf(o1.y) << 16);
    hv.w = (unsigned int)f2bf(o1.z) | ((unsigned int)f2bf(o1.w) << 16);
    *(uint4*)(hb + (size_t)d * 128 + lane * 8) = hv;
  }
}

// ---------------- pooling: emb[batch[n]] += h[n] (batch sorted) ----------------
__global__ __launch_bounds__(128) void pool_kernel(
    const float* __restrict__ h, const int* __restrict__ batch,
    float* __restrict__ emb, int N)
{
  int d = threadIdx.x;
  int n0 = blockIdx.x * 128;
  int n1 = min(n0 + 128, N);
  float acc = 0.f; int cur = -1;
  for (int n = n0; n < n1; n++) {
    int g = batch[n];
    if (g != cur) {
      if (cur >= 0) atomicAdd(&emb[(size_t)cur * 128 + d], acc);
      cur = g; acc = 0.f;
    }
    acc += h[(size_t)n * 128 + d];
  }
  if (cur >= 0) atomicAdd(&emb[(size_t)cur * 128 + d], acc);
}

// ---------------- final score ----------------
__global__ __launch_bounds__(128) void score_kernel(
    const float* __restrict__ hemb, const float* __restrict__ temb,
    const int* __restrict__ rels,
    const float* __restrict__ wqW, const float* __restrict__ wqb,
    const float* __restrict__ wkW, const float* __restrict__ wkb,
    const float* __restrict__ rel_emb, float* __restrict__ out)
{
  const int b = blockIdx.x, i = threadIdx.x;
  __shared__ float hs[128], ts[128], hnv[128], tnv[128], red[128];
  hs[i] = hemb[(size_t)b * 128 + i];
  ts[i] = temb[(size_t)b * 128 + i];
  __syncthreads();
  float qv = wqb[i], kv = wkb[i];
  for (int k = 0; k < 128; k++) {
    qv += hs[k] * wqW[k * 128 + i];
    kv += ts[k] * wkW[k * 128 + i];
  }
  float inter = tanhf(qv * kv);
  float hx = hs[i] + inter, tx2 = ts[i] + inter;

  red[i] = hx * hx; __syncthreads();
  for (int s = 64; s > 0; s >>= 1) { if (i < s) red[i] += red[i + s]; __syncthreads(); }
  float hnorm = fmaxf(sqrtf(red[0]), 1e-12f);
  __syncthreads();
  red[i] = tx2 * tx2; __syncthreads();
  for (int s = 64; s > 0; s >>= 1) { if (i < s) red[i] += red[i + s]; __syncthreads(); }
  float tnorm = fmaxf(sqrtf(red[0]), 1e-12f);
  __syncthreads();
  hnv[i] = hx / hnorm; tnv[i] = tx2 / tnorm;
  __syncthreads();

  const float* R = rel_emb + (size_t)rels[b] * 16384 + (size_t)i * 128;
  float dot = 0.f, nrm = 0.f;
  for (int j = 0; j < 128; j++) { float r = R[j]; dot += r * tnv[j]; nrm += r * r; }
  float contrib = hnv[i] * dot / fmaxf(sqrtf(nrm), 1e-12f);
  red[i] = contrib; __syncthreads();
  for (int s = 64; s > 0; s >>= 1) { if (i < s) red[i] += red[i + s]; __syncthreads(); }
  if (i == 0) out[b] = red[0];
}

extern "C" void kernel_launch(void* const* d_in, const int* in_sizes, int n_in,
                              void* d_out, int out_size, void* d_ws, size_t ws_size,
                              hipStream_t stream)
{
  const float* h_x     = (const float*)d_in[0];
  const int*   h_ei    = (const int*)d_in[1];
  const int*   h_batch = (const int*)d_in[2];
  const float* t_x     = (const float*)d_in[3];
  const int*   t_ei    = (const int*)d_in[4];
  const int*   t_batch = (const int*)d_in[5];
  const int*   rels    = (const int*)d_in[6];
  const float* lin0_W  = (const float*)d_in[7];
  const float* lin0_b  = (const float*)d_in[8];
  const float* Wq      = (const float*)d_in[9];
  const float* bq      = (const float*)d_in[10];
  const float* Wk      = (const float*)d_in[11];
  const float* bk      = (const float*)d_in[12];
  const float* Wv      = (const float*)d_in[13];
  const float* bv      = (const float*)d_in[14];
  const float* Ws      = (const float*)d_in[15];
  const float* bs      = (const float*)d_in[16];
  const float* wqW     = (const float*)d_in[17];
  const float* wqb     = (const float*)d_in[18];
  const float* wkW     = (const float*)d_in[19];
  const float* wkb     = (const float*)d_in[20];
  const float* rel_emb = (const float*)d_in[21];

  const int N = in_sizes[2];          // 50000
  const int E = in_sizes[1] / 2;      // 400000
  const int G = in_sizes[6];          // 512
  const int inF = in_sizes[7] / 128;  // 70

  char* ws = (char*)d_ws;
  size_t off = 0;
  auto alloc = [&](size_t bytes) -> void* {
    void* p = ws + off; off += (bytes + 255) & ~(size_t)255; return p;
  };
  float* hA            = (float*)alloc((size_t)N * 128 * 4);
  unsigned short* hbuf = (unsigned short*)alloc((size_t)N * 128 * 2);
  unsigned short* qb   = (unsigned short*)alloc((size_t)N * 512 * 2);
  unsigned short* kbuf = (unsigned short*)alloc((size_t)N * 512 * 2);
  unsigned short* vbuf = (unsigned short*)alloc((size_t)N * 512 * 2);
  unsigned short* BT   = (unsigned short*)alloc((size_t)3 * 1664 * 128 * 2);
  float* biascat       = (float*)alloc((size_t)3 * 1664 * 4);
  int* deg             = (int*)alloc((size_t)(N + 1) * 4);
  int* row_start       = (int*)alloc((size_t)(N + 1) * 4);
  int* cursor          = (int*)alloc((size_t)(N + 1) * 4);
  int* bsums           = (int*)alloc((size_t)1024 * 4);
  int* bsums_scan      = (int*)alloc((size_t)1024 * 4);
  int* csr_src         = (int*)alloc((size_t)E * 4);
  float* hEmb          = (float*)alloc((size_t)G * 128 * 4);
  float* tEmb          = (float*)alloc((size_t)G * 128 * 4);
  (void)ws_size; (void)n_in; (void)out_size;

  const int nScanBlocks = (N + 255) / 256;

  // Convert weights once per call (shared by both graphs)
  wcvt_kernel<<<3 * 1664, 128, 0, stream>>>(Wq, bq, Wk, bk, Wv, bv, Ws, bs, BT, biascat);

  for (int g = 0; g < 2; g++) {
    const float* x     = g ? t_x : h_x;
    const int*   ei    = g ? t_ei : h_ei;
    const int*   batch = g ? t_batch : h_batch;
    float*       emb   = g ? tEmb : hEmb;
    const int* srcp = ei;
    const int* dstp = ei + E;

    // --- build CSR (edges grouped by dst) ---
    hipMemsetAsync(deg, 0, (size_t)(N + 1) * 4, stream);
    hist_kernel<<<(E + 255) / 256, 256, 0, stream>>>(dstp, deg, E);
    scan_block_kernel<<<nScanBlocks, 256, 0, stream>>>(deg, row_start, bsums, N);
    scan_block_kernel<<<1, 256, 0, stream>>>(bsums, bsums_scan, nullptr, nScanBlocks);
    scan_finish_kernel<<<nScanBlocks, 256, 0, stream>>>(row_start, cursor, bsums_scan, N, E);
    scatter_kernel<<<(E + 255) / 256, 256, 0, stream>>>(srcp, dstp, cursor, csr_src, E);

    lin0_kernel<<<N, 128, 0, stream>>>(x, lin0_W, lin0_b, hA, hbuf, N, inF);
    for (int l = 0; l < 3; l++) {
      dim3 pg((N + 127) / 128, 13);
      proj_mfma_kernel<<<pg, 256, 0, stream>>>(hbuf,
          BT + (size_t)l * 1664 * 128, biascat + (size_t)l * 1664, N,
          qb, kbuf, vbuf, hA);
      node_attn_kernel<<<(N + 3) / 4, 256, 0, stream>>>(qb, kbuf, vbuf,
          row_start, csr_src, hA, hbuf, N);
    }
    hipMemsetAsync(emb, 0, (size_t)G * 128 * 4, stream);
    pool_kernel<<<(N + 127) / 128, 128, 0, stream>>>(hA, batch, emb, N);
  }

  score_kernel<<<G, 128, 0, stream>>>(hEmb, tEmb, rels, wqW, wqb, wkW, wkb,
                                      rel_emb, (float*)d_out);
}